// Round 2
// baseline (478.096 us; speedup 1.0000x reference)
//
#include <hip/hip_runtime.h>
#include <hip/hip_bf16.h>
#include <stdint.h>

typedef __attribute__((ext_vector_type(8))) short short8;
typedef __attribute__((ext_vector_type(4))) float floatx4;

#define B_TOT 1024
#define N_TOK 128
#define C_DIM 128
#define NHEAD 8
#define NW_MASK 64

#define MFMA(a, b, c) __builtin_amdgcn_mfma_f32_16x16x32_bf16((a), (b), (c), 0, 0, 0)

__device__ __forceinline__ float bf2f(ushort u) {
  union { uint32_t u; float f; } v; v.u = ((uint32_t)u) << 16; return v.f;
}
__device__ __forceinline__ ushort f2bf(float f) {
  uint32_t u = __float_as_uint(f);
  uint32_t r = (u + 0x7FFFu + ((u >> 16) & 1u)) >> 16;  // RNE
  return (ushort)r;
}
// exact 3-way Dekker split: f == hi + mid + lo + O(2^-26 |f|)
__device__ __forceinline__ void split3(float f, ushort& h, ushort& m, ushort& l) {
  h = f2bf(f);  float r  = f - bf2f(h);   // exact
  m = f2bf(r);  float r2 = r - bf2f(m);   // exact
  l = f2bf(r2);
}

// ---------------------------------------------------------------------------
// Kernel 1: gather relative-position bias -> bias_g[h][m][n] fp32 (exact copy)
// ---------------------------------------------------------------------------
__global__ void bias_gather_kernel(const int* __restrict__ rel_index,
                                   const float* __restrict__ table,
                                   float* __restrict__ bias_g) {
  int idx = blockIdx.x * 512 + threadIdx.x;   // 8*128*128 = 131072
  int h  = idx >> 14;
  int mn = idx & 16383;
  bias_g[idx] = table[rel_index[mn] * NHEAD + h];
}

// ---------------------------------------------------------------------------
// Kernel 2: fused window attention, fp32 in/out, split-bf16 MFMA internals.
// One block per batch window; 512 threads = 8 waves; wave w owns rows 16w..16w+15.
// LDS (155904 B):
//   xs  @0       [128][132] fp32   x tile                       67584
//   w-parts @67584: 7 x [16][136] bf16: wqh,wqm,wql,wkh,wkm,wkl,wvh  30464
//   wpt @98048   [128][40] bf16    Wproj^T slice (head pair)    10240
//   qs  @108288  [128][56] bf16    [qh|qm|ql]                   14336
//   ks  @122624  [128][56] bf16    [kh|km|kl]                   14336
//   vs  @136960  [128][17] fp32    v                             8704
//   xo  @145664  [128][40] bf16    attn out (head pair cols)    10240
// ---------------------------------------------------------------------------
__global__ __launch_bounds__(512)
void wattn_kernel(const float* __restrict__ x, const float* __restrict__ mask,
                  const float* __restrict__ Wq, const float* __restrict__ Wkv,
                  const float* __restrict__ Wproj, const float* __restrict__ bproj,
                  const float* __restrict__ bias_g, float* __restrict__ out) {
  extern __shared__ char smem[];
  float*  xs  = (float*)(smem);
  ushort* wqh = (ushort*)(smem + 67584);
  ushort* wqm = wqh + 2176;
  ushort* wql = wqh + 2 * 2176;
  ushort* wkh = wqh + 3 * 2176;
  ushort* wkm = wqh + 4 * 2176;
  ushort* wkl = wqh + 5 * 2176;
  ushort* wvh = wqh + 6 * 2176;
  ushort* wpt = (ushort*)(smem + 98048);
  ushort* qs  = (ushort*)(smem + 108288);
  ushort* ks  = (ushort*)(smem + 122624);
  float*  vs  = (float*)(smem + 136960);
  ushort* xo  = (ushort*)(smem + 145664);

  const int tid  = threadIdx.x;
  const int w    = tid >> 6;
  const int l    = tid & 63;
  const int quad = l >> 4;
  const int c    = l & 15;
  const int b    = blockIdx.x;
  const int wi   = b & (NW_MASK - 1);

  // ---- stage x_b (fp32) into LDS, coalesced float4
  {
    const float* xb = x + (size_t)b * (N_TOK * C_DIM);
    #pragma unroll
    for (int it = 0; it < 8; ++it) {
      int idx = it * 512 + tid;                  // 4096 float4 chunks
      int row = idx >> 5, c4 = (idx & 31) << 2;
      *(floatx4*)(xs + row * 132 + c4) = *(const floatx4*)(xb + row * 128 + c4);
    }
  }

  floatx4 oacc[8];
  #pragma unroll
  for (int j = 0; j < 8; ++j) oacc[j] = (floatx4){0.f, 0.f, 0.f, 0.f};

  for (int h = 0; h < NHEAD; ++h) {
    // ---- stage per-head W slices, 3-way split (q scaled by 0.25 exactly)
    #pragma unroll
    for (int it = 0; it < 4; ++it) {
      int pos = it * 512 + tid;                 // 2048 = 128 kk x 16 oc
      int kk = pos >> 4, oc = pos & 15;
      ushort a, bb, cc;
      float vq = Wq[kk * C_DIM + h * 16 + oc] * 0.25f;
      split3(vq, a, bb, cc);
      wqh[oc * 136 + kk] = a; wqm[oc * 136 + kk] = bb; wql[oc * 136 + kk] = cc;
      float vk = Wkv[kk * (2 * C_DIM) + h * 16 + oc];
      split3(vk, a, bb, cc);
      wkh[oc * 136 + kk] = a; wkm[oc * 136 + kk] = bb; wkl[oc * 136 + kk] = cc;
      float vv = Wkv[kk * (2 * C_DIM) + C_DIM + h * 16 + oc];
      wvh[oc * 136 + kk] = f2bf(vv);
    }
    if (h & 1) {  // Wproj^T slice for this head pair
      int hp = h >> 1;
      #pragma unroll
      for (int it = 0; it < 8; ++it) {
        int pos = it * 512 + tid;               // 4096 = 32 kk x 128 n
        int kk = pos >> 7, n = pos & 127;
        wpt[n * 40 + kk] = f2bf(Wproj[(hp * 32 + kk) * C_DIM + n]);
      }
    }
    __syncthreads();

    // ---- phase 2: q,k (6-term split) and v (2-term) projections
    {
      floatx4 aq = (floatx4){0.f,0.f,0.f,0.f};
      floatx4 ak = (floatx4){0.f,0.f,0.f,0.f};
      floatx4 av = (floatx4){0.f,0.f,0.f,0.f};
      const float* xrow = xs + (16 * w + c) * 132;
      #pragma unroll
      for (int kt = 0; kt < 8; ++kt) {
        int colb = kt * 16 + (quad & 1) * 8;
        floatx4 xa = *(const floatx4*)(xrow + colb);
        floatx4 xb2 = *(const floatx4*)(xrow + colb + 4);
        short8 hi8, mi8, lo8;
        #pragma unroll
        for (int jj = 0; jj < 8; ++jj) {
          float f = (jj < 4) ? xa[jj] : xb2[jj - 4];
          ushort hh, mm, ll; split3(f, hh, mm, ll);
          hi8[jj] = (short)hh; mi8[jj] = (short)mm; lo8[jj] = (short)ll;
        }
        short8 a1 = (quad < 2) ? hi8 : mi8;   // [xh|xm]
        short8 a3 = (quad < 2) ? hi8 : lo8;   // [xh|xl]
        int bo = kt * 16 + (quad & 1) * 8;
        short8 bq1 = *(const short8*)(wqh + c * 136 + bo);
        short8 bq2 = *(const short8*)(wqm + c * 136 + bo);
        short8 bq3 = *(const short8*)(((quad < 2) ? wql : wqh) + c * 136 + bo);
        aq = MFMA(a1, bq1, aq);  aq = MFMA(a1, bq2, aq);  aq = MFMA(a3, bq3, aq);
        short8 bk1 = *(const short8*)(wkh + c * 136 + bo);
        short8 bk2 = *(const short8*)(wkm + c * 136 + bo);
        short8 bk3 = *(const short8*)(((quad < 2) ? wkl : wkh) + c * 136 + bo);
        ak = MFMA(a1, bk1, ak);  ak = MFMA(a1, bk2, ak);  ak = MFMA(a3, bk3, ak);
        short8 bv1 = *(const short8*)(wvh + c * 136 + bo);
        av = MFMA(a1, bv1, av);                 // (xh+xm)*wvh
      }
      #pragma unroll
      for (int i = 0; i < 4; ++i) {
        int tok = 16 * w + 4 * quad + i;
        ushort a, bb, cc;
        split3(aq[i], a, bb, cc);
        qs[tok * 56 + c] = a; qs[tok * 56 + 16 + c] = bb; qs[tok * 56 + 32 + c] = cc;
        split3(ak[i], a, bb, cc);
        ks[tok * 56 + c] = a; ks[tok * 56 + 16 + c] = bb; ks[tok * 56 + 32 + c] = cc;
        vs[tok * 17 + c] = av[i];
      }
    }
    __syncthreads();

    // ---- phase 3: logits S = q.k^T (6 split terms) + bias + mask (fp32 init)
    floatx4 sacc[8];
    {
      const ushort* qrow = qs + (16 * w + c) * 56;
      short8 aq1 = *(const short8*)(qrow + quad * 8);                      // [qh|qm]
      short8 aq3 = *(const short8*)(qrow + ((quad < 2) ? quad * 8 : 16 + quad * 8)); // [qh|ql]
      #pragma unroll
      for (int j = 0; j < 8; ++j) {
        floatx4 acc;
        #pragma unroll
        for (int i = 0; i < 4; ++i) {
          int m = 16 * w + 4 * quad + i;
          int n = 16 * j + c;
          acc[i] = bias_g[(h * N_TOK + m) * N_TOK + n] +
                   mask[(wi * N_TOK + m) * N_TOK + n];
        }
        const ushort* krow = ks + (16 * j + c) * 56;
        int bo1 = (quad & 1) * 8;
        short8 b1 = *(const short8*)(krow + bo1);            // [kh|kh]
        short8 b2 = *(const short8*)(krow + 16 + bo1);       // [km|km]
        short8 b3 = *(const short8*)(krow + ((quad < 2) ? 32 + quad * 8
                                                        : (quad - 2) * 8)); // [kl|kh]
        acc = MFMA(aq1, b1, acc);
        acc = MFMA(aq1, b2, acc);
        acc = MFMA(aq3, b3, acc);
        sacc[j] = acc;
      }
    }

    // ---- phase 3b: register softmax denom + top-2, weighted V gather
    #pragma unroll
    for (int i = 0; i < 4; ++i) {
      float m1 = sacc[0][i]; int i1 = c;
      float m2 = -__builtin_inff(); int i2 = -1;
      float psum = 1.0f;
      #pragma unroll
      for (int j = 1; j < 8; ++j) {
        float v = sacc[j][i]; int col = 16 * j + c;
        bool g1 = v > m1;
        float e = __expf(g1 ? (m1 - v) : (v - m1));
        psum = g1 ? (psum * e + 1.0f) : (psum + e);
        bool g2 = (!g1) && (v > m2);
        m2 = g1 ? m1 : (g2 ? v : m2);
        i2 = g1 ? i1 : (g2 ? col : i2);
        m1 = g1 ? v : m1;
        i1 = g1 ? col : i1;
      }
      #pragma unroll
      for (int d = 1; d < 16; d <<= 1) {
        float om1 = __shfl_xor(m1, d); int oi1 = __shfl_xor(i1, d);
        float om2 = __shfl_xor(m2, d); int oi2 = __shfl_xor(i2, d);
        float ops = __shfl_xor(psum, d);
        bool aw = (m1 > om1) || (m1 == om1 && i1 < oi1);
        float M  = aw ? m1 : om1;  int I  = aw ? i1 : oi1;
        float lv = aw ? om1 : m1;  int li = aw ? oi1 : i1;
        float sv = aw ? m2 : om2;  int si = aw ? i2 : oi2;
        bool sb = (sv > lv) || (sv == lv && si < li);
        float e = __expf(lv - M);
        psum = (aw ? psum : ops) + (aw ? ops : psum) * e;
        m1 = M; i1 = I;
        m2 = sb ? sv : lv; i2 = sb ? si : li;
      }
      float p1 = 1.0f / psum;
      float p2 = __expf(m2 - m1) * p1;
      int tok = 16 * w + 4 * quad + i;
      float o = p1 * vs[i1 * 17 + c] + p2 * vs[i2 * 17 + c];
      xo[tok * 40 + (h & 1) * 16 + c] = f2bf(o);
    }

    // ---- phase 4: out-projection, K=32 per head pair, persistent acc
    if (h & 1) {
      short8 a = *(const short8*)(xo + (16 * w + c) * 40 + quad * 8);
      #pragma unroll
      for (int j = 0; j < 8; ++j) {
        short8 bf = *(const short8*)(wpt + (16 * j + c) * 40 + quad * 8);
        oacc[j] = MFMA(a, bf, oacc[j]);
      }
    }
    __syncthreads();
  }

  // ---- epilogue: + bproj, fp32 store
  #pragma unroll
  for (int j = 0; j < 8; ++j) {
    float bp = bproj[16 * j + c];
    #pragma unroll
    for (int i = 0; i < 4; ++i) {
      int row = 16 * w + 4 * quad + i;
      out[((size_t)b * N_TOK + row) * C_DIM + 16 * j + c] = oacc[j][i] + bp;
    }
  }
}

extern "C" void kernel_launch(void* const* d_in, const int* in_sizes, int n_in,
                              void* d_out, int out_size, void* d_ws, size_t ws_size,
                              hipStream_t stream) {
  const float* x     = (const float*)d_in[0];
  const float* mask  = (const float*)d_in[1];
  const float* Wq    = (const float*)d_in[2];
  const float* Wkv   = (const float*)d_in[3];
  const float* Wproj = (const float*)d_in[4];
  const float* bproj = (const float*)d_in[5];
  const float* btab  = (const float*)d_in[6];
  const int*   ridx  = (const int*)d_in[7];
  float* outp   = (float*)d_out;
  float* bias_g = (float*)d_ws;   // 8*128*128 fp32 = 512 KB

  (void)in_sizes; (void)n_in; (void)out_size; (void)ws_size;

  hipFuncSetAttribute(reinterpret_cast<const void*>(wattn_kernel),
                      hipFuncAttributeMaxDynamicSharedMemorySize, 155904);

  bias_gather_kernel<<<256, 512, 0, stream>>>(ridx, btab, bias_g);
  wattn_kernel<<<B_TOT, 512, 155904, stream>>>(x, mask, Wq, Wkv, Wproj, bproj,
                                               bias_g, outp);
}